// Round 27
// baseline (94.979 us; speedup 1.0000x reference)
//
#include <hip/hip_runtime.h>
#include <hip/hip_bf16.h>

#define THREADS 256

// d_out = concat(corr3, corr2, corr1, corr0), fp32.
// corr[bb, pi, pj, i, j] = sum_c a[bb,c,i,j] * bpad[bb,c, i+pi-4, j+pj-4]
// Input mapping: d_in = rgb0, depth0, rgb1, depth1, ... (interleaved).
#define OFF3 0
#define OFF2 127008        // 8*81*14*14
#define OFF1 635040        // OFF2 + 8*81*28*28
#define OFF0 2667168       // OFF1 + 8*81*56*56

// fused-grid segmentation — ALL levels MFMA now (R27)
#define GB_L0 6272         // 8 bb * 112 rows * 7 x-tiles    (/8 = 784 = 1 bb)
#define GB_L1 1792         // 8 bb * 56 rows * 4 x-tiles     (/8 = 224 = 1 bb)
#define GB_L2 224          // 8 bb * 28 rows (row-Gram)      (/8 = 28  = 1 bb)
#define GB_L3 112          // 8 bb * 14 rows (row-Gram)      (/8 = 14  = 1 bb)
#define GB_TOT (GB_L0 + GB_L1 + GB_L2 + GB_L3)   // 8400

// max over: L2 row-Gram 32*272+32*32 = 9728 | x-tile 32*216+32*16 = 7424
#define SMEM_FLOATS 9728

typedef __attribute__((ext_vector_type(8))) short bf16x8;
typedef __attribute__((ext_vector_type(4))) float f32x4;

// Global zero page: OOB/halo/pad staging lanes load from here.
__device__ __attribute__((aligned(64))) const float g_zeropage[16] = {};

__device__ __forceinline__ void gload16(const float* g, float* l) {
    __builtin_amdgcn_global_load_lds(
        (const __attribute__((address_space(1))) void*)g,
        (__attribute__((address_space(3))) void*)l, 16, 0, 0);
}

__device__ __forceinline__ short bf16s(float f) {
    __hip_bfloat16 h = __float2bfloat16(f);
    return *reinterpret_cast<short*>(&h);
}

// ---------------- x-tile MFMA path (L0, L1) — R27 new ----------------
// Block = (bb, row i, x-tile jt): x = i*W + 16*jt + m, m in [0,16).
// y-window = 9 rows (i-4..i+4) x 24 cols (16jt-4 .. 16jt+19), staged as
// N = 216 (stride 216/ch, slots >=216 are pad, guarded). 14 N-tiles over
// 4 waves (nt = wid + 4t). K = C/32 ksteps of mfma_f32_16x16x32_bf16.
// Spill x (L1 last tile) -> value-identical duplicate writes (benign, as
// proven for L2/L3 row spill in R25/R26). OOB y staged zero -> D=0 writes
// match the reference's zero padding.
template<int C, int H, int W, int JT>
__device__ __forceinline__ void corr_xtile_mfma(const float* __restrict__ a,
                                                const float* __restrict__ b,
                                                float* __restrict__ out,
                                                int blk, float* __restrict__ smem)
{
    constexpr int HW  = H * W;
    constexpr int NKS = C / 32;
    const int bb = blk / (H * JT);
    const int r2 = blk - bb * (H * JT);
    const int i  = r2 / JT;
    const int jt = r2 - i * JT;
    const int j0 = 16 * jt;
    const int x0 = i * W + j0;

    const int tid = threadIdx.x;
    const int lane = tid & 63, wid = tid >> 6;
    const int kgrp = lane >> 4, mn = lane & 15;
    const float* zp = g_zeropage;

    f32x4 accv[4];
    #pragma unroll
    for (int t = 0; t < 4; ++t) accv[t] = (f32x4){0.f, 0.f, 0.f, 0.f};

    for (int ks = 0; ks < NKS; ++ks) {
        __syncthreads();                       // previous readers done
        const float* bp = b + (size_t)(bb * C + ks * 32) * HW;
        // B: 32ch * 9 rows * 6 f4 = 1728 slots, stride 216 floats/ch
        #pragma unroll
        for (int it = 0; it < 7; ++it) {
            const int f = tid + it * 256;
            if (f < 1728) {
                const int c  = f / 54;
                const int f2 = f - 54 * c;
                const int r  = f2 / 6;
                const int q  = f2 - 6 * r;
                const int ry = i - 4 + r;
                const int cy = j0 - 4 + 4 * q;
                const bool ok = ((unsigned)ry < (unsigned)H)
                                && (cy >= 0) && (cy <= W - 4);
                const float* src = ok ? (bp + c * HW + ry * W + cy) : zp;
                gload16(src, smem + (size_t)4 * f);
            }
        }
        // A: 32ch * 4 f4 = 128 slots at offset 6912
        if (tid < 128) {
            const int c = tid >> 2, q = tid & 3;
            const int x = x0 + 4 * q;
            const bool ok = (x <= HW - 4);
            const float* src = ok ? (a + (size_t)(bb * C + ks * 32 + c) * HW + x)
                                  : zp;
            gload16(src, smem + (size_t)(4 * 1728) + (size_t)4 * tid);
        }
        __syncthreads();                       // drains vmcnt(0): data ready

        bf16x8 afr;
        #pragma unroll
        for (int e = 0; e < 8; ++e)
            afr[e] = bf16s(smem[6912 + (kgrp * 8 + e) * 16 + mn]);

        #pragma unroll
        for (int t = 0; t < 4; ++t) {
            const int nt = wid + 4 * t;
            if (nt < 14) {
                bf16x8 bfr;
                #pragma unroll
                for (int e = 0; e < 8; ++e) {
                    const int n = nt * 16 + mn;
                    bfr[e] = (n < 216)
                        ? bf16s(smem[(kgrp * 8 + e) * 216 + n]) : (short)0;
                }
                accv[t] = __builtin_amdgcn_mfma_f32_16x16x32_bf16(
                    afr, bfr, accv[t], 0, 0, 0);
            }
        }
    }

    // Epilogue: D[m][n], m = (lane>>4)*4 + r, n = lane&15 within tile.
    const int mrow0 = (lane >> 4) * 4;
    #pragma unroll
    for (int t = 0; t < 4; ++t) {
        const int nt = wid + 4 * t;
        if (nt < 14) {
            const int n = nt * 16 + mn;
            if (n < 216) {
                const int ry = n / 24;
                const int cy = n - 24 * ry;
                const int yi = i - 4 + ry;
                const int yj = j0 - 4 + cy;
                #pragma unroll
                for (int r = 0; r < 4; ++r) {
                    const int m = mrow0 + r;
                    const int x = x0 + m;
                    if (x < HW) {
                        const int xi = x / W;
                        const int xj = x - W * xi;
                        const int pi = yi - xi + 4;
                        const int pj = yj - xj + 4;
                        if ((unsigned)pi < 9u && (unsigned)pj < 9u)
                            out[(size_t)((bb * 9 + pi) * 9 + pj) * HW + x]
                                = accv[t][r];
                    }
                }
            }
        }
    }
}

// ---------------- row-Gram MFMA path for L3 (C=512, 14x14) — proven R25 ----
__device__ __forceinline__ void corr_l3_mfma(const float* __restrict__ a,
                                             const float* __restrict__ b,
                                             float* __restrict__ out,
                                             int blk, float* __restrict__ smem)
{
    constexpr int C = 512, HW = 196, W = 14;
    const int bb = blk / 14, i = blk % 14;
    const int y0a = ((i - 4) * W) & ~3;
    const int x0a = (i * W) & ~3;
    const int off = i * W - x0a;
    const int tid = threadIdx.x;
    const int lane = tid & 63, wid = tid >> 6;

    float* bl = smem;                          // [32][144]
    float* al = smem + 32 * 144;               // [32][20]
    const float* zp = g_zeropage;
    const float* ab = a + (size_t)bb * C * HW;
    const float* bbase = b + (size_t)bb * C * HW;

    const int nt0 = wid * 2;
    const int ntc = (wid == 3) ? 3 : 2;

    f32x4 accv[3];
    #pragma unroll
    for (int t = 0; t < 3; ++t) accv[t] = (f32x4){0.f, 0.f, 0.f, 0.f};

    const int kgrp = lane >> 4;
    const int mn   = lane & 15;

    for (int ks = 0; ks < 16; ++ks) {
        __syncthreads();
        const float* bp = bbase + (size_t)(ks * 32) * HW;
        #pragma unroll
        for (int it = 0; it < 5; ++it) {
            const int f = tid + it * 256;
            if (f < 1152) {
                const int c = f / 36, q = f - 36 * c;
                const int y = y0a + 4 * q;
                const float* src = (y >= 0 && y <= 192) ? (bp + c * HW + y) : zp;
                gload16(src, smem + (size_t)4 * f);
            }
        }
        if (tid < 160) {
            const int c = tid / 5, q = tid - 5 * c;
            const int x = x0a + 4 * q;
            const float* src = (x <= 192) ? (ab + (size_t)(ks * 32 + c) * HW + x)
                                          : zp;
            gload16(src, smem + (size_t)4 * 1152 + (size_t)4 * tid);
        }
        __syncthreads();

        bf16x8 afr;
        #pragma unroll
        for (int e = 0; e < 8; ++e)
            afr[e] = bf16s(al[(kgrp * 8 + e) * 20 + off + mn]);

        #pragma unroll
        for (int t = 0; t < 3; ++t) {
            if (t < ntc) {
                const int nt = nt0 + t;
                bf16x8 bfr;
                #pragma unroll
                for (int e = 0; e < 8; ++e)
                    bfr[e] = bf16s(bl[(kgrp * 8 + e) * 144 + nt * 16 + mn]);
                accv[t] = __builtin_amdgcn_mfma_f32_16x16x32_bf16(
                    afr, bfr, accv[t], 0, 0, 0);
            }
        }
    }

    const int mrow0 = (lane >> 4) * 4;
    #pragma unroll
    for (int t = 0; t < 3; ++t) {
        if (t < ntc) {
            const int nt = nt0 + t;
            const int y  = y0a + nt * 16 + mn;
            const int ys = y + 56;
            const int yq = ys / 14;
            const int yi = yq - 4;
            const int yj = ys - 14 * yq;
            #pragma unroll
            for (int r = 0; r < 4; ++r) {
                const int m = mrow0 + r;
                const int x = i * 14 + m;
                if (x < 196) {
                    const int xi = x / 14;
                    const int xj = x - 14 * xi;
                    const int pi = yi - xi + 4;
                    const int pj = yj - xj + 4;
                    if ((unsigned)pi < 9u && (unsigned)pj < 9u)
                        out[(size_t)((bb * 9 + pi) * 9 + pj) * HW + x] = accv[t][r];
                }
            }
        }
    }
}

// ---------------- row-Gram MFMA path for L2 (C=256, 28x28) — proven R26 ----
__device__ __forceinline__ void corr_l2_mfma(const float* __restrict__ a,
                                             const float* __restrict__ b,
                                             float* __restrict__ out,
                                             int blk, float* __restrict__ smem)
{
    constexpr int C = 256, HW = 784, W = 28;
    const int bb = blk / 28, i = blk % 28;
    const int x0 = i * 28;
    const int y0 = x0 - 116;
    const int tid = threadIdx.x;
    const int lane = tid & 63, wid = tid >> 6;

    float* bl = smem;                          // [32][272]
    float* al = smem + 32 * 272;               // [32][32]
    const float* zp = g_zeropage;
    const float* ab = a + (size_t)bb * C * HW;
    const float* bbase = b + (size_t)bb * C * HW;

    f32x4 accv[9];
    #pragma unroll
    for (int t = 0; t < 9; ++t) accv[t] = (f32x4){0.f, 0.f, 0.f, 0.f};

    const int kgrp = lane >> 4;
    const int mn   = lane & 15;

    for (int ks = 0; ks < 8; ++ks) {
        __syncthreads();
        const float* bp = bbase + (size_t)(ks * 32) * HW;
        #pragma unroll
        for (int it = 0; it < 9; ++it) {
            const int f = tid + it * 256;
            if (f < 2176) {
                const int c = f / 68, q = f - 68 * c;
                const int y = y0 + 4 * q;
                const float* src = (y >= 0 && y <= HW - 4) ? (bp + c * HW + y) : zp;
                gload16(src, smem + (size_t)4 * f);
            }
        }
        {
            const int c = tid >> 3, q = tid & 7;
            const int x = x0 + 4 * q;
            const float* src = (x <= HW - 4) ? (ab + (size_t)(ks * 32 + c) * HW + x)
                                             : zp;
            gload16(src, smem + (size_t)4 * 2176 + (size_t)4 * tid);
        }
        __syncthreads();

        bf16x8 afr[2];
        #pragma unroll
        for (int mt = 0; mt < 2; ++mt)
            #pragma unroll
            for (int e = 0; e < 8; ++e)
                afr[mt][e] = bf16s(al[(kgrp * 8 + e) * 32 + mt * 16 + mn]);

        #pragma unroll
        for (int t = 0; t < 9; ++t) {
            const int p = wid + 4 * t;
            if (p < 34) {
                const int mt = p & 1, nt = p >> 1;
                bf16x8 bfr;
                #pragma unroll
                for (int e = 0; e < 8; ++e)
                    bfr[e] = bf16s(bl[(kgrp * 8 + e) * 272 + nt * 16 + mn]);
                accv[t] = __builtin_amdgcn_mfma_f32_16x16x32_bf16(
                    afr[mt], bfr, accv[t], 0, 0, 0);
            }
        }
    }

    const int mrow0 = (lane >> 4) * 4;
    #pragma unroll
    for (int t = 0; t < 9; ++t) {
        const int p = wid + 4 * t;
        if (p < 34) {
            const int mt = p & 1, nt = p >> 1;
            const int y  = y0 + nt * 16 + mn;
            const int ys = y + 224;
            const int yq = ys / 28;
            const int yi = yq - 8;
            const int yj = ys - 28 * yq;
            #pragma unroll
            for (int r = 0; r < 4; ++r) {
                const int m = mt * 16 + mrow0 + r;
                const int x = x0 + m;
                if (x < HW) {
                    const int xi = x / 28;
                    const int xj = x - 28 * xi;
                    const int pi = yi - xi + 4;
                    const int pj = yj - xj + 4;
                    if ((unsigned)pi < 9u && (unsigned)pj < 9u)
                        out[(size_t)((bb * 9 + pi) * 9 + pj) * HW + x] = accv[t][r];
                }
            }
        }
    }
}

// All four levels MFMA in ONE dispatch; no workspace, no reduce, every output
// element written exactly once by its home block (spill writes duplicate
// identical values). Per-segment XCD swizzle: each XCD owns exactly ONE
// batch-image per level (784/224/28/14 blocks) -> b-slices fit per-XCD L2.
__global__ void __launch_bounds__(THREADS)
corr_fused(const float* __restrict__ a0, const float* __restrict__ b0,
           const float* __restrict__ a1, const float* __restrict__ b1,
           const float* __restrict__ a2, const float* __restrict__ b2,
           const float* __restrict__ a3, const float* __restrict__ b3,
           float* __restrict__ out)
{
    __shared__ float smem[SMEM_FLOATS];
    const int bid = blockIdx.x;
    if (bid < GB_L0) {
        const int blk = (bid % 8) * (GB_L0 / 8) + bid / 8;
        corr_xtile_mfma<64, 112, 112, 7>(a0, b0, out + OFF0, blk, smem);
    } else if (bid < GB_L0 + GB_L1) {
        const int r = bid - GB_L0;
        const int blk = (r % 8) * (GB_L1 / 8) + r / 8;
        corr_xtile_mfma<128, 56, 56, 4>(a1, b1, out + OFF1, blk, smem);
    } else if (bid < GB_L0 + GB_L1 + GB_L2) {
        const int r = bid - (GB_L0 + GB_L1);
        const int blk = (r % 8) * (GB_L2 / 8) + r / 8;
        corr_l2_mfma(a2, b2, out + OFF2, blk, smem);
    } else {
        const int r = bid - (GB_L0 + GB_L1 + GB_L2);
        const int blk = (r % 8) * (GB_L3 / 8) + r / 8;
        corr_l3_mfma(a3, b3, out + OFF3, blk, smem);
    }
}

extern "C" void kernel_launch(void* const* d_in, const int* in_sizes, int n_in,
                              void* d_out, int out_size, void* d_ws, size_t ws_size,
                              hipStream_t stream) {
    // setup_inputs() dict order: rgb0, depth0, rgb1, depth1, rgb2, depth2, rgb3, depth3
    const float* a0 = (const float*)d_in[0];
    const float* b0 = (const float*)d_in[1];
    const float* a1 = (const float*)d_in[2];
    const float* b1 = (const float*)d_in[3];
    const float* a2 = (const float*)d_in[4];
    const float* b2 = (const float*)d_in[5];
    const float* a3 = (const float*)d_in[6];
    const float* b3 = (const float*)d_in[7];
    float* out = (float*)d_out;

    hipLaunchKernelGGL(corr_fused, dim3(GB_TOT), dim3(THREADS), 0, stream,
                       a0, b0, a1, b1, a2, b2, a3, b3, out);
}

// Round 28
// 60.119 us; speedup vs baseline: 1.5798x; 1.5798x over previous
//
#include <hip/hip_runtime.h>
#include <hip/hip_bf16.h>

#define THREADS 256

// d_out = concat(corr3, corr2, corr1, corr0), fp32.
// corr[bb, pi, pj, i, j] = sum_c a[bb,c,i,j] * bpad[bb,c, i+pi-4, j+pj-4]
// Input mapping: d_in = rgb0, depth0, rgb1, depth1, ... (interleaved).
#define OFF3 0
#define OFF2 127008        // 8*81*14*14
#define OFF1 635040        // OFF2 + 8*81*28*28
#define OFF0 2667168       // OFF1 + 8*81*56*56

// Workspace layout (floats): L1 partials | L2 partials (L3 is MFMA-direct)
#define N1 2032128
#define N2 508032
#define N3 127008
#define WS_L1 0
#define WS_L2 (2 * N1)
#define WS_L3 (WS_L2 + 4 * N2)
#define WS_FLOATS (WS_L3 + 16 * N3)
#define WS_BYTES ((size_t)WS_FLOATS * 4)

// fused-grid segmentation
#define GB_L0 448          // 8 bb * 28 i-tiles * 2 j-tiles   (/8 = 56)
#define GB_L1 224          // 8 * 14 * 1 * 2 chunks           (/8 = 28)
#define GB_L2 224          // 8 * 7 * 1 * 4 chunks            (/8 = 28)
#define GB_L3 112          // 8 bb * 14 rows (MFMA)           (/8 = 14)
#define GB_TOT (GB_L0 + GB_L1 + GB_L2 + GB_L3)   // 1008

// 3 buffers * max scalar BUFSZ (3072 floats) = 9216 floats = 36.9 KB
// (MFMA L3 path reuses the same array: needs 5248 floats.)
#define SMEM_FLOATS 9216

typedef __attribute__((ext_vector_type(8))) short bf16x8;
typedef __attribute__((ext_vector_type(4))) float f32x4;

// Global zero page: OOB/halo/pad staging lanes load from here.
__device__ __attribute__((aligned(64))) const float g_zeropage[16] = {};

__global__ void __launch_bounds__(THREADS)
zero_region_kernel(float* __restrict__ p, int n) {
    int i = blockIdx.x * blockDim.x + threadIdx.x;
    int stride = gridDim.x * blockDim.x;
    for (; i < n; i += stride) p[i] = 0.f;
}

__device__ __forceinline__ void gload16(const float* g, float* l) {
    __builtin_amdgcn_global_load_lds(
        (const __attribute__((address_space(1))) void*)g,
        (__attribute__((address_space(3))) void*)l, 16, 0, 0);
}
__device__ __forceinline__ void gload4(const float* g, float* l) {
    __builtin_amdgcn_global_load_lds(
        (const __attribute__((address_space(1))) void*)g,
        (__attribute__((address_space(3))) void*)l, 4, 0, 0);
}

__device__ __forceinline__ short bf16s(float f) {
    __hip_bfloat16 h = __float2bfloat16(f);
    return *reinterpret_cast<short*>(&h);
}

template<int N> __device__ __forceinline__ void wait_vm_lgkm0() {
    static_assert(N >= 0 && N <= 8, "unsupported count");
    if constexpr (N == 0) asm volatile("s_waitcnt vmcnt(0) lgkmcnt(0)" ::: "memory");
    else if constexpr (N == 1) asm volatile("s_waitcnt vmcnt(1) lgkmcnt(0)" ::: "memory");
    else if constexpr (N == 2) asm volatile("s_waitcnt vmcnt(2) lgkmcnt(0)" ::: "memory");
    else if constexpr (N == 3) asm volatile("s_waitcnt vmcnt(3) lgkmcnt(0)" ::: "memory");
    else if constexpr (N == 4) asm volatile("s_waitcnt vmcnt(4) lgkmcnt(0)" ::: "memory");
    else if constexpr (N == 5) asm volatile("s_waitcnt vmcnt(5) lgkmcnt(0)" ::: "memory");
    else if constexpr (N == 6) asm volatile("s_waitcnt vmcnt(6) lgkmcnt(0)" ::: "memory");
    else if constexpr (N == 7) asm volatile("s_waitcnt vmcnt(7) lgkmcnt(0)" ::: "memory");
    else                       asm volatile("s_waitcnt vmcnt(8) lgkmcnt(0)" ::: "memory");
}

// ---------------- scalar path (L0/L1/L2) ----------------
template<int C, int H, int W, int TI, int TW, int SJ, int STRIPS, int CHUNKS,
         int CB, int MODE>
__device__ __forceinline__ void corr_level(const float* __restrict__ a,
                                           const float* __restrict__ b,
                                           float* __restrict__ out,
                                           int blk, float* __restrict__ smem)
{
    constexpr int PER_I = 9 * STRIPS;
    constexpr int USED  = TI * PER_I;
    constexpr bool F4   = (W % 4 == 0) && (TW % 4 == 0) && (SJ % 4 == 0);
    constexpr int BWQ0  = (TW + 8 + 3) / 4 + 1;
    constexpr int BWQ   = (BWQ0 % 2 == 0) ? BWQ0 + 1 : BWQ0;
    constexpr int BW_   = F4 ? BWQ * 4 : (((TW + 8 + 1) / 2) * 2);
    constexpr bool F2   = !F4 && (SJ % 2 == 0) && (TW % 2 == 0);
    constexpr int BROWS = TI + 8;
    constexpr int CCH   = C / CHUNKS;
    constexpr int HT    = (H + TI - 1) / TI;
    constexpr int WT    = W / TW;
    constexpr int NOUT  = 8 * 81 * H * W;
    constexpr int HW    = H * W;
    constexpr int BPC   = BROWS * BW_;
    constexpr int APC   = TI * TW;
    constexpr int NG    = CCH / CB;

    constexpr int F4PR = BW_ / 4;
    constexpr int NBF4 = BROWS * F4PR;
    constexpr int TOT4 = CB * NBF4;
    constexpr int K4   = (TOT4 + THREADS - 1) / THREADS;
    constexpr int TOTS = CB * BPC;
    constexpr int KS   = (TOTS + THREADS - 1) / THREADS;
    constexpr int A4PR = TW / 4;
    constexpr int NAF4 = TI * A4PR;
    constexpr int ATOT4 = CB * NAF4;
    constexpr int KA4  = (ATOT4 + THREADS - 1) / THREADS;
    constexpr int ATOTS = CB * APC;
    constexpr int KAS  = (ATOTS + THREADS - 1) / THREADS;

    constexpr int A_OFF = F4 ? (K4 * THREADS * 4) : (KS * THREADS);
    constexpr int BUFSZ = F4 ? ((K4 + KA4) * THREADS * 4) : ((KS + KAS) * THREADS);
    constexpr int KTOT  = F4 ? (K4 + KA4) : (KS + KAS);

    static_assert(USED <= THREADS && SJ * STRIPS == TW && CCH % CB == 0, "geom");
    static_assert(NG >= 2 && 3 * BUFSZ <= SMEM_FLOATS, "pipeline/smem");

    const int ch = blk % CHUNKS;
    int t = blk / CHUNKS;
    const int jt = t % WT; t /= WT;
    const int it = t % HT;
    const int bb = t / HT;
    const int i0 = it * TI;
    const int jb = jt * TW;

    const int tid = threadIdx.x;
    const int ii  = tid / PER_I;
    const int rem = tid - ii * PER_I;
    const int pi  = rem / STRIPS;
    const int s   = rem - pi * STRIPS;
    const int j0  = s * SJ;
    const bool active = (tid < USED) && ((H % TI == 0) || (i0 + ii) < H);

    const int c0 = ch * CCH;
    const float* __restrict__ bp = b + (size_t)(bb * C + c0) * HW;
    const float* __restrict__ ap = a + (size_t)(bb * C + c0) * HW;
    const float* zp = g_zeropage;

    float acc[9][SJ];
    #pragma unroll
    for (int p = 0; p < 9; ++p)
        #pragma unroll
        for (int u = 0; u < SJ; ++u) acc[p][u] = 0.f;

    const int wbase = tid & ~63;

    auto stage = [&](int cg, float* buf) {
        const float* gb = bp + (size_t)(cg * CB) * HW;
        const float* ga = ap + (size_t)(cg * CB) * HW;
        if constexpr (F4) {
            #pragma unroll
            for (int k = 0; k < K4; ++k) {
                const int f = tid + k * THREADS;
                const int cb  = f / NBF4;
                const int f2  = f - cb * NBF4;
                const int row = f2 / F4PR;
                const int c4  = f2 - row * F4PR;
                const int r   = i0 + row - 4;
                const int jj  = jb + (c4 - 1) * 4;
                const bool ok = (f < TOT4) && ((unsigned)r < (unsigned)H)
                                && (jj >= 0) && (jj <= W - 4);
                const float* src = ok ? (gb + cb * HW + r * W + jj) : zp;
                gload16(src, buf + (size_t)(k * THREADS + wbase) * 4);
            }
            #pragma unroll
            for (int k = 0; k < KA4; ++k) {
                const int f = tid + k * THREADS;
                const int cb  = f / NAF4;
                const int f2  = f - cb * NAF4;
                const int row = f2 / A4PR;
                const int c4  = f2 - row * A4PR;
                const bool ok = (f < ATOT4) && ((H % TI == 0) || (i0 + row) < H);
                const float* src = ok ? (ga + cb * HW + (i0 + row) * W + jb + c4 * 4)
                                      : zp;
                gload16(src, buf + A_OFF + (size_t)(k * THREADS + wbase) * 4);
            }
        } else {
            #pragma unroll
            for (int k = 0; k < KS; ++k) {
                const int f = tid + k * THREADS;
                const int cb  = f / BPC;
                const int f2  = f - cb * BPC;
                const int row = f2 / BW_;
                const int col = f2 - row * BW_;
                const int r   = i0 + row - 4;
                const int jj  = jb + col - 4;
                const bool ok = (f < TOTS) && ((unsigned)r < (unsigned)H)
                                && ((unsigned)jj < (unsigned)W);
                const float* src = ok ? (gb + cb * HW + r * W + jj) : zp;
                gload4(src, buf + (k * THREADS + wbase));
            }
            #pragma unroll
            for (int k = 0; k < KAS; ++k) {
                const int f = tid + k * THREADS;
                const int cb  = f / APC;
                const int f2  = f - cb * APC;
                const int row = f2 / TW;
                const int col = f2 - row * TW;
                const bool ok = (f < ATOTS) && ((H % TI == 0) || (i0 + row) < H);
                const float* src = ok ? (ga + cb * HW + (i0 + row) * W + jb + col)
                                      : zp;
                gload4(src, buf + A_OFF + (k * THREADS + wbase));
            }
        }
    };
    auto compute = [&](const float* buf) {
        if (!active) return;
        #pragma unroll
        for (int cb = 0; cb < CB; ++cb) {
            float breg[SJ + 8];
            float areg[SJ];
            const float* bbase = &buf[cb * BPC + (ii + pi) * BW_ + j0];
            const float* abase = &buf[A_OFF + cb * APC + ii * TW + j0];
            if constexpr (F4) {
                #pragma unroll
                for (int k = 0; k < (SJ + 8) / 4; ++k) {
                    float4 v = *reinterpret_cast<const float4*>(&bbase[4 * k]);
                    breg[4*k+0] = v.x; breg[4*k+1] = v.y;
                    breg[4*k+2] = v.z; breg[4*k+3] = v.w;
                }
                #pragma unroll
                for (int u = 0; u < SJ / 4; ++u) {
                    float4 v = *reinterpret_cast<const float4*>(&abase[4 * u]);
                    areg[4*u+0] = v.x; areg[4*u+1] = v.y;
                    areg[4*u+2] = v.z; areg[4*u+3] = v.w;
                }
            } else if constexpr (F2) {
                #pragma unroll
                for (int k = 0; k < (SJ + 8) / 2; ++k) {
                    float2 v = *reinterpret_cast<const float2*>(&bbase[2 * k]);
                    breg[2*k+0] = v.x; breg[2*k+1] = v.y;
                }
                #pragma unroll
                for (int u = 0; u < SJ / 2; ++u) {
                    float2 v = *reinterpret_cast<const float2*>(&abase[2 * u]);
                    areg[2*u+0] = v.x; areg[2*u+1] = v.y;
                }
            } else {
                #pragma unroll
                for (int k = 0; k < SJ + 8; ++k) breg[k] = bbase[k];
                #pragma unroll
                for (int u = 0; u < SJ; ++u) areg[u] = abase[u];
            }
            #pragma unroll
            for (int pj = 0; pj < 9; ++pj)
                #pragma unroll
                for (int u = 0; u < SJ; ++u)
                    acc[pj][u] = fmaf(areg[u], breg[u + pj], acc[pj][u]);
        }
    };

    float* bufA = smem;
    float* bufB = smem + BUFSZ;
    float* bufC = smem + 2 * BUFSZ;

    stage(0, bufA);
    stage(1, bufB);
    for (int cg = 0; cg < NG; ++cg) {
        if (cg < NG - 1) wait_vm_lgkm0<KTOT>();
        else             wait_vm_lgkm0<0>();
        __builtin_amdgcn_s_barrier();
        __builtin_amdgcn_sched_barrier(0);
        if (cg + 2 < NG) stage(cg + 2, bufC);
        compute(bufA);
        float* tp = bufA; bufA = bufB; bufB = bufC; bufC = tp;
    }

    if (active) {
        const int i = i0 + ii;
        float* obase = out;
        if constexpr (MODE == 1) obase = out + (size_t)ch * NOUT;
        #pragma unroll
        for (int pj = 0; pj < 9; ++pj) {
            float* o = obase + ((size_t)((bb * 9 + pi) * 9 + pj) * H + i) * W + jb + j0;
            if constexpr (MODE == 2) {
                #pragma unroll
                for (int u = 0; u < SJ; ++u) atomicAdd(&o[u], acc[pj][u]);
            } else if constexpr (F4) {
                #pragma unroll
                for (int u = 0; u < SJ / 4; ++u) {
                    float4 v;
                    v.x = acc[pj][4*u+0]; v.y = acc[pj][4*u+1];
                    v.z = acc[pj][4*u+2]; v.w = acc[pj][4*u+3];
                    *reinterpret_cast<float4*>(&o[4 * u]) = v;
                }
            } else {
                #pragma unroll
                for (int u = 0; u < SJ; ++u) o[u] = acc[pj][u];
            }
        }
    }
}

// ---------------- MFMA path for L3 (C=512, 14x14) — proven in R25 ----------
__device__ __forceinline__ void corr_l3_mfma(const float* __restrict__ a,
                                             const float* __restrict__ b,
                                             float* __restrict__ out,
                                             int blk, float* __restrict__ smem)
{
    constexpr int C = 512, HW = 196, W = 14;
    const int bb = blk / 14, i = blk % 14;
    const int y0a = ((i - 4) * W) & ~3;
    const int x0a = (i * W) & ~3;
    const int off = i * W - x0a;
    const int tid = threadIdx.x;
    const int lane = tid & 63, wid = tid >> 6;

    float* bl = smem;                          // [32][144]
    float* al = smem + 32 * 144;               // [32][20]
    const float* zp = g_zeropage;
    const float* ab = a + (size_t)bb * C * HW;
    const float* bbase = b + (size_t)bb * C * HW;

    const int nt0 = wid * 2;
    const int ntc = (wid == 3) ? 3 : 2;

    f32x4 accv[3];
    #pragma unroll
    for (int t = 0; t < 3; ++t) accv[t] = (f32x4){0.f, 0.f, 0.f, 0.f};

    const int kgrp = lane >> 4;
    const int mn   = lane & 15;

    for (int ks = 0; ks < 16; ++ks) {
        __syncthreads();
        const float* bp = bbase + (size_t)(ks * 32) * HW;
        #pragma unroll
        for (int it = 0; it < 5; ++it) {
            const int f = tid + it * 256;
            if (f < 1152) {
                const int c = f / 36, q = f - 36 * c;
                const int y = y0a + 4 * q;
                const float* src = (y >= 0 && y <= 192) ? (bp + c * HW + y) : zp;
                gload16(src, smem + (size_t)4 * f);
            }
        }
        if (tid < 160) {
            const int c = tid / 5, q = tid - 5 * c;
            const int x = x0a + 4 * q;
            const float* src = (x <= 192) ? (ab + (size_t)(ks * 32 + c) * HW + x)
                                          : zp;
            gload16(src, smem + (size_t)4 * 1152 + (size_t)4 * tid);
        }
        __syncthreads();

        bf16x8 afr;
        #pragma unroll
        for (int e = 0; e < 8; ++e)
            afr[e] = bf16s(al[(kgrp * 8 + e) * 20 + off + mn]);

        #pragma unroll
        for (int t = 0; t < 3; ++t) {
            if (t < ntc) {
                const int nt = nt0 + t;
                bf16x8 bfr;
                #pragma unroll
                for (int e = 0; e < 8; ++e)
                    bfr[e] = bf16s(bl[(kgrp * 8 + e) * 144 + nt * 16 + mn]);
                accv[t] = __builtin_amdgcn_mfma_f32_16x16x32_bf16(
                    afr, bfr, accv[t], 0, 0, 0);
            }
        }
    }

    const int mrow0 = (lane >> 4) * 4;
    #pragma unroll
    for (int t = 0; t < 3; ++t) {
        if (t < ntc) {
            const int nt = nt0 + t;
            const int y  = y0a + nt * 16 + mn;
            const int ys = y + 56;
            const int yq = ys / 14;
            const int yi = yq - 4;
            const int yj = ys - 14 * yq;
            #pragma unroll
            for (int r = 0; r < 4; ++r) {
                const int m = mrow0 + r;
                const int x = i * 14 + m;
                if (x < 196) {
                    const int xi = x / 14;
                    const int xj = x - 14 * xi;
                    const int pi = yi - xi + 4;
                    const int pj = yj - xj + 4;
                    if ((unsigned)pi < 9u && (unsigned)pj < 9u)
                        out[(size_t)((bb * 9 + pi) * 9 + pj) * HW + x] = accv[t][r];
                }
            }
        }
    }
}

// All four levels in ONE dispatch. L3 is the MFMA path (direct store, no ws).
// Per-segment XCD swizzle (R24 win) retained for all segments.
// PMODE: 1 = ws partial-sum path, 2 = atomic fallback (L0/L3 unaffected).
template<int PMODE>
__global__ void __launch_bounds__(THREADS)
corr_fused(const float* __restrict__ a0, const float* __restrict__ b0,
           const float* __restrict__ a1, const float* __restrict__ b1,
           const float* __restrict__ a2, const float* __restrict__ b2,
           const float* __restrict__ a3, const float* __restrict__ b3,
           float* __restrict__ out, float* __restrict__ ws)
{
    __shared__ float smem[SMEM_FLOATS];
    const int bid = blockIdx.x;
    if (bid < GB_L0) {
        const int blk = (bid % 8) * (GB_L0 / 8) + bid / 8;
        corr_level<64, 112, 112, 4, 56, 8, 7, 1, 2, 0>(
            a0, b0, out + OFF0, blk, smem);
    } else if (bid < GB_L0 + GB_L1) {
        const int r = bid - GB_L0;
        const int blk = (r % 8) * (GB_L1 / 8) + r / 8;
        corr_level<128, 56, 56, 4, 56, 8, 7, 2, 2, PMODE>(
            a1, b1, PMODE == 1 ? ws + WS_L1 : out + OFF1, blk, smem);
    } else if (bid < GB_L0 + GB_L1 + GB_L2) {
        const int r = bid - (GB_L0 + GB_L1);
        const int blk = (r % 8) * (GB_L2 / 8) + r / 8;
        corr_level<256, 28, 28, 4, 28, 4, 7, 4, 2, PMODE>(
            a2, b2, PMODE == 1 ? ws + WS_L2 : out + OFF2, blk, smem);
    } else {
        const int r = bid - (GB_L0 + GB_L1 + GB_L2);
        const int blk = (r % 8) * (GB_L3 / 8) + r / 8;
        corr_l3_mfma(a3, b3, out + OFF3, blk, smem);
    }
}

// Reduce L2 (4 chunks) and L1 (2 chunks) partials into d_out.
__global__ void __launch_bounds__(THREADS)
reduce_all_kernel(const float* __restrict__ ws, float* __restrict__ out)
{
    const int blk = blockIdx.x;
    const float4* src; float4* dst; int n4, chunks, nb, base;
    if (blk < 128) { src = (const float4*)(ws + WS_L2); dst = (float4*)(out + OFF2);
                     n4 = N2 / 4; chunks = 4; nb = 128; base = 0; }
    else           { src = (const float4*)(ws + WS_L1); dst = (float4*)(out + OFF1);
                     n4 = N1 / 4; chunks = 2; nb = 288; base = 128; }
    for (int i = (blk - base) * THREADS + threadIdx.x; i < n4; i += nb * THREADS) {
        float4 sv = src[i];
        for (int k = 1; k < chunks; ++k) {
            float4 tv = src[(size_t)k * n4 + i];
            sv.x += tv.x; sv.y += tv.y; sv.z += tv.z; sv.w += tv.w;
        }
        dst[i] = sv;
    }
}

extern "C" void kernel_launch(void* const* d_in, const int* in_sizes, int n_in,
                              void* d_out, int out_size, void* d_ws, size_t ws_size,
                              hipStream_t stream) {
    // setup_inputs() dict order: rgb0, depth0, rgb1, depth1, rgb2, depth2, rgb3, depth3
    const float* a0 = (const float*)d_in[0];
    const float* b0 = (const float*)d_in[1];
    const float* a1 = (const float*)d_in[2];
    const float* b1 = (const float*)d_in[3];
    const float* a2 = (const float*)d_in[4];
    const float* b2 = (const float*)d_in[5];
    const float* a3 = (const float*)d_in[6];
    const float* b3 = (const float*)d_in[7];
    float* out = (float*)d_out;
    float* ws  = (float*)d_ws;

    if (ws_size >= WS_BYTES) {
        hipLaunchKernelGGL((corr_fused<1>), dim3(GB_TOT), dim3(THREADS), 0, stream,
                           a0, b0, a1, b1, a2, b2, a3, b3, out, ws);
        hipLaunchKernelGGL(reduce_all_kernel, dim3(416), dim3(THREADS), 0, stream,
                           ws, out);
    } else {
        // fallback: zero the atomic region (corr2|corr1), atomics for L1/L2
        hipLaunchKernelGGL(zero_region_kernel, dim3(512), dim3(THREADS), 0, stream,
                           out + OFF2, OFF0 - OFF2);
        hipLaunchKernelGGL((corr_fused<2>), dim3(GB_TOT), dim3(THREADS), 0, stream,
                           a0, b0, a1, b1, a2, b2, a3, b3, out, ws);
    }
}